// Round 1
// baseline (276.915 us; speedup 1.0000x reference)
//
#include <hip/hip_runtime.h>

// GlobalKMaxPool2d: per row of 3136 fp32, sum of top-8 values.
// One wave (64 lanes) per row. Per-lane sorted top-8 in registers via
// branchless compare-exchange insert, then bitonic shfl_xor butterfly merge.

#define CE(a, b) { float _hi = fmaxf((a), (b)); float _lo = fminf((a), (b)); (a) = _hi; (b) = _lo; }

#define INS(v) { float _t = (v); \
    CE(r0, _t); CE(r1, _t); CE(r2, _t); CE(r3, _t); \
    CE(r4, _t); CE(r5, _t); CE(r6, _t); CE(r7, _t); }

__global__ __launch_bounds__(256) void topk8_sum_kernel(
    const float* __restrict__ x, float* __restrict__ out, int rows) {
    const int HW = 3136;  // 56*56
    const int gw = (int)((blockIdx.x * blockDim.x + threadIdx.x) >> 6);  // global wave = row
    const int lane = (int)(threadIdx.x & 63);
    if (gw >= rows) return;

    const float* __restrict__ row = x + (size_t)gw * HW;

    float r0 = -INFINITY, r1 = -INFINITY, r2 = -INFINITY, r3 = -INFINITY,
          r4 = -INFINITY, r5 = -INFINITY, r6 = -INFINITY, r7 = -INFINITY;

    // Phase 1: 12 coalesced float4 iterations cover 12*256 = 3072 elements.
    // lane i loads [it*256 + i*4 .. +3] -> 64 lanes * 16B = 1 KiB/instr, aligned
    // (row base = gw*12544 bytes, 16B-aligned).
    #pragma unroll
    for (int it = 0; it < 12; ++it) {
        float4 v = *reinterpret_cast<const float4*>(row + it * 256 + lane * 4);
        INS(v.x); INS(v.y); INS(v.z); INS(v.w);
    }
    // Phase 2: tail 64 elements, one scalar load per lane.
    INS(row[3072 + lane]);

    // Butterfly merge: top-8 of two sorted desc 8-lists a,b is the multiset
    // {max(a[i], b[7-i])} (first CE stage of bitonic-16 merge); result is a
    // bitonic-8 sequence -> re-sort desc with 12 CEs (distances 4,2,1).
    #pragma unroll
    for (int m = 1; m <= 16; m <<= 1) {
        float b0 = __shfl_xor(r0, m, 64);
        float b1 = __shfl_xor(r1, m, 64);
        float b2 = __shfl_xor(r2, m, 64);
        float b3 = __shfl_xor(r3, m, 64);
        float b4 = __shfl_xor(r4, m, 64);
        float b5 = __shfl_xor(r5, m, 64);
        float b6 = __shfl_xor(r6, m, 64);
        float b7 = __shfl_xor(r7, m, 64);
        float m0 = fmaxf(r0, b7);
        float m1 = fmaxf(r1, b6);
        float m2 = fmaxf(r2, b5);
        float m3 = fmaxf(r3, b4);
        float m4 = fmaxf(r4, b3);
        float m5 = fmaxf(r5, b2);
        float m6 = fmaxf(r6, b1);
        float m7 = fmaxf(r7, b0);
        // bitonic-8 sort (descending)
        CE(m0, m4); CE(m1, m5); CE(m2, m6); CE(m3, m7);
        CE(m0, m2); CE(m1, m3); CE(m4, m6); CE(m5, m7);
        CE(m0, m1); CE(m2, m3); CE(m4, m5); CE(m6, m7);
        r0 = m0; r1 = m1; r2 = m2; r3 = m3;
        r4 = m4; r5 = m5; r6 = m6; r7 = m7;
    }

    // Final step (xor 32): only the sum of the merged top-8 is needed.
    {
        float b0 = __shfl_xor(r0, 32, 64);
        float b1 = __shfl_xor(r1, 32, 64);
        float b2 = __shfl_xor(r2, 32, 64);
        float b3 = __shfl_xor(r3, 32, 64);
        float b4 = __shfl_xor(r4, 32, 64);
        float b5 = __shfl_xor(r5, 32, 64);
        float b6 = __shfl_xor(r6, 32, 64);
        float b7 = __shfl_xor(r7, 32, 64);
        float sum = fmaxf(r0, b7) + fmaxf(r1, b6) + fmaxf(r2, b5) + fmaxf(r3, b4)
                  + fmaxf(r4, b3) + fmaxf(r5, b2) + fmaxf(r6, b1) + fmaxf(r7, b0);
        if (lane == 0) out[gw] = sum;
    }
}

extern "C" void kernel_launch(void* const* d_in, const int* in_sizes, int n_in,
                              void* d_out, int out_size, void* d_ws, size_t ws_size,
                              hipStream_t stream) {
    const float* x = (const float*)d_in[0];
    float* out = (float*)d_out;
    const int rows = out_size;  // 64*256 = 16384; one wave per row
    const int threads = 256;    // 4 waves/block
    const int blocks = (rows * 64 + threads - 1) / threads;
    topk8_sum_kernel<<<blocks, threads, 0, stream>>>(x, out, rows);
}

// Round 2
// 276.594 us; speedup vs baseline: 1.0012x; 1.0012x over previous
//
#include <hip/hip_runtime.h>

// GlobalKMaxPool2d: per row of 3136 fp32, sum of top-8 values.
// One wave (64 lanes) per row. Per-lane: sort each float4 (5 CEs), bitonic
// top-8 merge into one of TWO independent sorted-8 lists (A/B for ILP),
// then combine + shfl_xor butterfly merge across lanes.

#define CE(a, b) { float _hi = fmaxf((a), (b)); float _lo = fminf((a), (b)); (a) = _hi; (b) = _lo; }

// sort 4 values descending (s0 >= s1 >= s2 >= s3), 5 CEs
#define SORT4(s0, s1, s2, s3) { CE(s0, s2); CE(s1, s3); CE(s0, s1); CE(s2, s3); CE(s1, s2); }

// keep top-8 of (sorted-desc-8 list l0..l7) U (sorted-desc-4 s0..s3):
// first bitonic-16 stage vs [-inf x4, s3, s2, s1, s0] = 4 maxes, result is
// bitonic-8 -> 12-CE bitonic resort (desc).
#define MERGE4(l0, l1, l2, l3, l4, l5, l6, l7, s0, s1, s2, s3) { \
    l4 = fmaxf(l4, s3); l5 = fmaxf(l5, s2); l6 = fmaxf(l6, s1); l7 = fmaxf(l7, s0); \
    CE(l0, l4); CE(l1, l5); CE(l2, l6); CE(l3, l7); \
    CE(l0, l2); CE(l1, l3); CE(l4, l6); CE(l5, l7); \
    CE(l0, l1); CE(l2, l3); CE(l4, l5); CE(l6, l7); }

// bitonic-8 resort (input bitonic, output desc), 12 CEs
#define RESORT8(m0, m1, m2, m3, m4, m5, m6, m7) { \
    CE(m0, m4); CE(m1, m5); CE(m2, m6); CE(m3, m7); \
    CE(m0, m2); CE(m1, m3); CE(m4, m6); CE(m5, m7); \
    CE(m0, m1); CE(m2, m3); CE(m4, m5); CE(m6, m7); }

__global__ __launch_bounds__(256) void topk8_sum_kernel(
    const float* __restrict__ x, float* __restrict__ out, int rows) {
    const int gw = (int)((blockIdx.x * blockDim.x + threadIdx.x) >> 6);  // row
    const int lane = (int)(threadIdx.x & 63);
    if (gw >= rows) return;

    const float* __restrict__ row = x + (size_t)gw * 3136;

    float a0 = -INFINITY, a1 = -INFINITY, a2 = -INFINITY, a3 = -INFINITY,
          a4 = -INFINITY, a5 = -INFINITY, a6 = -INFINITY, a7 = -INFINITY;
    float b0 = -INFINITY, b1 = -INFINITY, b2 = -INFINITY, b3 = -INFINITY,
          b4 = -INFINITY, b5 = -INFINITY, b6 = -INFINITY, b7 = -INFINITY;

    // 12 coalesced float4 loads/lane cover 12*256 = 3072 elements of the row.
    // Two loads issued per iteration; even float4 -> list A, odd -> list B
    // (independent dependence chains).
    #pragma unroll
    for (int it = 0; it < 6; ++it) {
        float4 u = *reinterpret_cast<const float4*>(row + (2 * it) * 256 + lane * 4);
        float4 v = *reinterpret_cast<const float4*>(row + (2 * it + 1) * 256 + lane * 4);
        float u0 = u.x, u1 = u.y, u2 = u.z, u3 = u.w;
        float v0 = v.x, v1 = v.y, v2 = v.z, v3 = v.w;
        SORT4(u0, u1, u2, u3);
        SORT4(v0, v1, v2, v3);
        MERGE4(a0, a1, a2, a3, a4, a5, a6, a7, u0, u1, u2, u3);
        MERGE4(b0, b1, b2, b3, b4, b5, b6, b7, v0, v1, v2, v3);
    }

    // tail: element 3072+lane, 8-CE insertion into list B
    {
        float t = row[3072 + lane];
        CE(b0, t); CE(b1, t); CE(b2, t); CE(b3, t);
        CE(b4, t); CE(b5, t); CE(b6, t); CE(b7, t);
    }

    // combine A and B: top-8 of two sorted-desc-8 = {max(a_i, b_{7-i})},
    // result bitonic -> resort
    float r0 = fmaxf(a0, b7), r1 = fmaxf(a1, b6), r2 = fmaxf(a2, b5), r3 = fmaxf(a3, b4),
          r4 = fmaxf(a4, b3), r5 = fmaxf(a5, b2), r6 = fmaxf(a6, b1), r7 = fmaxf(a7, b0);
    RESORT8(r0, r1, r2, r3, r4, r5, r6, r7);

    // cross-lane butterfly merge (xor 1,2,4,8,16): keep sorted for next step
    #pragma unroll
    for (int m = 1; m <= 16; m <<= 1) {
        float c0 = __shfl_xor(r0, m, 64);
        float c1 = __shfl_xor(r1, m, 64);
        float c2 = __shfl_xor(r2, m, 64);
        float c3 = __shfl_xor(r3, m, 64);
        float c4 = __shfl_xor(r4, m, 64);
        float c5 = __shfl_xor(r5, m, 64);
        float c6 = __shfl_xor(r6, m, 64);
        float c7 = __shfl_xor(r7, m, 64);
        float m0 = fmaxf(r0, c7), m1 = fmaxf(r1, c6), m2 = fmaxf(r2, c5), m3 = fmaxf(r3, c4),
              m4 = fmaxf(r4, c3), m5 = fmaxf(r5, c2), m6 = fmaxf(r6, c1), m7 = fmaxf(r7, c0);
        RESORT8(m0, m1, m2, m3, m4, m5, m6, m7);
        r0 = m0; r1 = m1; r2 = m2; r3 = m3;
        r4 = m4; r5 = m5; r6 = m6; r7 = m7;
    }

    // final step (xor 32): only the sum is needed, no resort
    {
        float c0 = __shfl_xor(r0, 32, 64);
        float c1 = __shfl_xor(r1, 32, 64);
        float c2 = __shfl_xor(r2, 32, 64);
        float c3 = __shfl_xor(r3, 32, 64);
        float c4 = __shfl_xor(r4, 32, 64);
        float c5 = __shfl_xor(r5, 32, 64);
        float c6 = __shfl_xor(r6, 32, 64);
        float c7 = __shfl_xor(r7, 32, 64);
        float sum = fmaxf(r0, c7) + fmaxf(r1, c6) + fmaxf(r2, c5) + fmaxf(r3, c4)
                  + fmaxf(r4, c3) + fmaxf(r5, c2) + fmaxf(r6, c1) + fmaxf(r7, c0);
        if (lane == 0) out[gw] = sum;
    }
}

extern "C" void kernel_launch(void* const* d_in, const int* in_sizes, int n_in,
                              void* d_out, int out_size, void* d_ws, size_t ws_size,
                              hipStream_t stream) {
    const float* x = (const float*)d_in[0];
    float* out = (float*)d_out;
    const int rows = out_size;  // 64*256 = 16384; one wave per row
    const int threads = 256;    // 4 waves/block
    const int blocks = (rows * 64 + threads - 1) / threads;
    topk8_sum_kernel<<<blocks, threads, 0, stream>>>(x, out, rows);
}